// Round 2
// baseline (220.219 us; speedup 1.0000x reference)
//
#include <hip/hip_runtime.h>

#define EPS 1e-10f

// One row (D floats = ITER*256 float4) per 256-thread block.
// All 5*ITER independent 16B loads are issued before any dependent compute,
// giving enough memory-level parallelism to cover HBM latency.
template<int ITER>
__global__ __launch_bounds__(256) void loss_row_kernel(
    const float* __restrict__ input,
    const float* __restrict__ target,
    const float* __restrict__ weight,
    const float* __restrict__ sub_target,
    const float* __restrict__ target_pre,
    const float* __restrict__ sub_obrT,
    double* __restrict__ acc)   // acc[0]=wmse sum, acc[1]=wcl sum
{
    const int row  = blockIdx.x;
    const int base = row * (ITER * 256) + threadIdx.x;   // float4 index

    const float4* __restrict__ in4 = (const float4*)input;
    const float4* __restrict__ tg4 = (const float4*)target;
    const float4* __restrict__ st4 = (const float4*)sub_target;
    const float4* __restrict__ tp4 = (const float4*)target_pre;
    const float4* __restrict__ so4 = (const float4*)sub_obrT;

    const float w  = weight[row];    // wave-uniform scalar load
    const float w2 = w * w;

    // Issue ALL loads first (independent, compile-time offsets).
    float4 x[ITER], t[ITER], st[ITER], tp[ITER], so[ITER];
#pragma unroll
    for (int k = 0; k < ITER; ++k) {
        int i = base + k * 256;
        x[k]  = in4[i];
        t[k]  = tg4[i];
        st[k] = st4[i];
        tp[k] = tp4[i];
        so[k] = so4[i];
    }

    float s_mse = 0.0f;
    float s_wcl = 0.0f;
#pragma unroll
    for (int k = 0; k < ITER; ++k) {
        float d0 = t[k].x - x[k].x, d1 = t[k].y - x[k].y;
        float d2 = t[k].z - x[k].z, d3 = t[k].w - x[k].w;
        s_mse += w2 * (d0 * d0);
        s_mse += w2 * (d1 * d1);
        s_mse += w2 * (d2 * d2);
        s_mse += w2 * (d3 * d3);

        float b0 = st[k].x * __logf(tp[k].x + EPS) + (1.0f - st[k].x) * __logf(1.0f - tp[k].x + EPS);
        float b1 = st[k].y * __logf(tp[k].y + EPS) + (1.0f - st[k].y) * __logf(1.0f - tp[k].y + EPS);
        float b2 = st[k].z * __logf(tp[k].z + EPS) + (1.0f - st[k].z) * __logf(1.0f - tp[k].z + EPS);
        float b3 = st[k].w * __logf(tp[k].w + EPS) + (1.0f - st[k].w) * __logf(1.0f - tp[k].w + EPS);
        s_wcl += fabsf(b0 * so[k].x);
        s_wcl += fabsf(b1 * so[k].y);
        s_wcl += fabsf(b2 * so[k].z);
        s_wcl += fabsf(b3 * so[k].w);
    }

    // wave (64-lane) shuffle reduction
    for (int off = 32; off > 0; off >>= 1) {
        s_mse += __shfl_down(s_mse, off, 64);
        s_wcl += __shfl_down(s_wcl, off, 64);
    }

    __shared__ float lds_mse[4];
    __shared__ float lds_wcl[4];
    int lane = threadIdx.x & 63;
    int wid  = threadIdx.x >> 6;
    if (lane == 0) {
        lds_mse[wid] = s_mse;
        lds_wcl[wid] = s_wcl;
    }
    __syncthreads();
    if (threadIdx.x == 0) {
        float bm = lds_mse[0] + lds_mse[1] + lds_mse[2] + lds_mse[3];
        float bc = lds_wcl[0] + lds_wcl[1] + lds_wcl[2] + lds_wcl[3];
        atomicAdd(&acc[0], (double)bm);
        atomicAdd(&acc[1], (double)bc);
    }
}

// Generic grid-stride fallback for shapes the specialized kernel can't take.
__global__ __launch_bounds__(256) void loss_reduce_generic(
    const float* __restrict__ input,
    const float* __restrict__ target,
    const float* __restrict__ weight,
    const float* __restrict__ sub_target,
    const float* __restrict__ target_pre,
    const float* __restrict__ sub_obrT,
    double* __restrict__ acc,
    int total, int D)
{
    float s_mse = 0.0f, s_wcl = 0.0f;
    int idx = blockIdx.x * blockDim.x + threadIdx.x;
    int stride = gridDim.x * blockDim.x;
    for (int i = idx; i < total; i += stride) {
        float w = weight[i / D];
        float d = target[i] - input[i];
        s_mse += w * w * d * d;
        float st = sub_target[i], tp = target_pre[i];
        float b = st * __logf(tp + EPS) + (1.0f - st) * __logf(1.0f - tp + EPS);
        s_wcl += fabsf(b * sub_obrT[i]);
    }
    for (int off = 32; off > 0; off >>= 1) {
        s_mse += __shfl_down(s_mse, off, 64);
        s_wcl += __shfl_down(s_wcl, off, 64);
    }
    __shared__ float lds_mse[4];
    __shared__ float lds_wcl[4];
    int lane = threadIdx.x & 63;
    int wid  = threadIdx.x >> 6;
    if (lane == 0) { lds_mse[wid] = s_mse; lds_wcl[wid] = s_wcl; }
    __syncthreads();
    if (threadIdx.x == 0) {
        atomicAdd(&acc[0], (double)(lds_mse[0] + lds_mse[1] + lds_mse[2] + lds_mse[3]));
        atomicAdd(&acc[1], (double)(lds_wcl[0] + lds_wcl[1] + lds_wcl[2] + lds_wcl[3]));
    }
}

__global__ void loss_finalize_kernel(const double* __restrict__ acc,
                                     float* __restrict__ out,
                                     double inv_count)
{
    if (threadIdx.x == 0 && blockIdx.x == 0) {
        out[0] = (float)(acc[0] * inv_count);
        out[1] = (float)(acc[1] * inv_count);
    }
}

extern "C" void kernel_launch(void* const* d_in, const int* in_sizes, int n_in,
                              void* d_out, int out_size, void* d_ws, size_t ws_size,
                              hipStream_t stream) {
    const float* input      = (const float*)d_in[0];
    const float* target     = (const float*)d_in[1];
    const float* weight     = (const float*)d_in[2];
    const float* sub_target = (const float*)d_in[3];
    const float* target_pre = (const float*)d_in[4];
    const float* sub_obrT   = (const float*)d_in[5];
    float* out = (float*)d_out;

    const int ND = in_sizes[0];      // N*D
    const int N  = in_sizes[2];      // weight length
    const int D  = ND / N;

    double* acc = (double*)d_ws;
    hipMemsetAsync(acc, 0, 2 * sizeof(double), stream);

    if (D == 2048) {
        // 512 float4 per row -> ITER=2 with 256 threads
        loss_row_kernel<2><<<N, 256, 0, stream>>>(
            input, target, weight, sub_target, target_pre, sub_obrT, acc);
    } else if (D == 1024) {
        loss_row_kernel<1><<<N, 256, 0, stream>>>(
            input, target, weight, sub_target, target_pre, sub_obrT, acc);
    } else if (D == 4096) {
        loss_row_kernel<4><<<N, 256, 0, stream>>>(
            input, target, weight, sub_target, target_pre, sub_obrT, acc);
    } else {
        int grid = (ND + 255) / 256;
        if (grid > 4096) grid = 4096;
        if (grid < 1) grid = 1;
        loss_reduce_generic<<<grid, 256, 0, stream>>>(
            input, target, weight, sub_target, target_pre, sub_obrT, acc, ND, D);
    }

    loss_finalize_kernel<<<acc != nullptr ? 1 : 1, 1, 0, stream>>>(acc, out, 1.0 / (double)ND);
}

// Round 3
// 87.046 us; speedup vs baseline: 2.5299x; 2.5299x over previous
//
#include <hip/hip_runtime.h>

#define EPS 1e-10f

// Software-pipelined grid-stride reduction, fully static trip count.
// Requires: n4 == gridDim.x * 256 * NITER  (checked by host).
// SHIFT: weight row = float4_index >> SHIFT  (d4 = D/4 = 1<<SHIFT).
// Prefetch distance 1: next batch's 6 loads are issued and PINNED
// (sched_barrier) before the current batch's compute, so ~6 vector loads
// stay in flight per wave throughout.
template<int NITER, int SHIFT>
__global__ __launch_bounds__(256) void loss_pipe_kernel(
    const float4* __restrict__ in4,
    const float4* __restrict__ tg4,
    const float*  __restrict__ weight,
    const float4* __restrict__ st4,
    const float4* __restrict__ tp4,
    const float4* __restrict__ so4,
    double* __restrict__ acc,
    int stride4)                    // gridDim.x * 256
{
    int i = blockIdx.x * 256 + threadIdx.x;

    float s_mse = 0.0f;
    float s_wcl = 0.0f;

    // prologue: batch 0
    float4 cx = in4[i];
    float4 ct = tg4[i];
    float4 cs = st4[i];
    float4 cp = tp4[i];
    float4 co = so4[i];
    float  cw = weight[i >> SHIFT];

#pragma unroll
    for (int k = 0; k < NITER; ++k) {
        float4 nx, nt, ns, nq, no;
        float  nw = 0.0f;
        const int j = i + stride4;
        if (k + 1 < NITER) {
            nx = in4[j];
            nt = tg4[j];
            ns = st4[j];
            nq = tp4[j];
            no = so4[j];
            nw = weight[j >> SHIFT];
        }
        // Pin: all next-batch loads issued BEFORE current-batch compute;
        // compiler may not sink them past this point.
        __builtin_amdgcn_sched_barrier(0);

        const float w2 = cw * cw;
        float d0 = ct.x - cx.x, d1 = ct.y - cx.y;
        float d2 = ct.z - cx.z, d3 = ct.w - cx.w;
        s_mse += w2 * (d0 * d0);
        s_mse += w2 * (d1 * d1);
        s_mse += w2 * (d2 * d2);
        s_mse += w2 * (d3 * d3);

        float b0 = cs.x * __logf(cp.x + EPS) + (1.0f - cs.x) * __logf(1.0f - cp.x + EPS);
        float b1 = cs.y * __logf(cp.y + EPS) + (1.0f - cs.y) * __logf(1.0f - cp.y + EPS);
        float b2 = cs.z * __logf(cp.z + EPS) + (1.0f - cs.z) * __logf(1.0f - cp.z + EPS);
        float b3 = cs.w * __logf(cp.w + EPS) + (1.0f - cs.w) * __logf(1.0f - cp.w + EPS);
        s_wcl += fabsf(b0 * co.x);
        s_wcl += fabsf(b1 * co.y);
        s_wcl += fabsf(b2 * co.z);
        s_wcl += fabsf(b3 * co.w);

        if (k + 1 < NITER) {
            cx = nx; ct = nt; cs = ns; cp = nq; co = no; cw = nw;
            i = j;
        }
    }

    // wave (64-lane) shuffle reduction
    for (int off = 32; off > 0; off >>= 1) {
        s_mse += __shfl_down(s_mse, off, 64);
        s_wcl += __shfl_down(s_wcl, off, 64);
    }

    __shared__ float lds_mse[4];
    __shared__ float lds_wcl[4];
    int lane = threadIdx.x & 63;
    int wid  = threadIdx.x >> 6;
    if (lane == 0) {
        lds_mse[wid] = s_mse;
        lds_wcl[wid] = s_wcl;
    }
    __syncthreads();
    if (threadIdx.x == 0) {
        float bm = lds_mse[0] + lds_mse[1] + lds_mse[2] + lds_mse[3];
        float bc = lds_wcl[0] + lds_wcl[1] + lds_wcl[2] + lds_wcl[3];
        atomicAdd(&acc[0], (double)bm);
        atomicAdd(&acc[1], (double)bc);
    }
}

// Generic grid-stride fallback for arbitrary shapes.
__global__ __launch_bounds__(256) void loss_reduce_generic(
    const float* __restrict__ input,
    const float* __restrict__ target,
    const float* __restrict__ weight,
    const float* __restrict__ sub_target,
    const float* __restrict__ target_pre,
    const float* __restrict__ sub_obrT,
    double* __restrict__ acc,
    int total, int D)
{
    float s_mse = 0.0f, s_wcl = 0.0f;
    int idx = blockIdx.x * blockDim.x + threadIdx.x;
    int stride = gridDim.x * blockDim.x;
    for (int i = idx; i < total; i += stride) {
        float w = weight[i / D];
        float d = target[i] - input[i];
        s_mse += w * w * d * d;
        float st = sub_target[i], tp = target_pre[i];
        float b = st * __logf(tp + EPS) + (1.0f - st) * __logf(1.0f - tp + EPS);
        s_wcl += fabsf(b * sub_obrT[i]);
    }
    for (int off = 32; off > 0; off >>= 1) {
        s_mse += __shfl_down(s_mse, off, 64);
        s_wcl += __shfl_down(s_wcl, off, 64);
    }
    __shared__ float lds_mse[4];
    __shared__ float lds_wcl[4];
    int lane = threadIdx.x & 63;
    int wid  = threadIdx.x >> 6;
    if (lane == 0) { lds_mse[wid] = s_mse; lds_wcl[wid] = s_wcl; }
    __syncthreads();
    if (threadIdx.x == 0) {
        atomicAdd(&acc[0], (double)(lds_mse[0] + lds_mse[1] + lds_mse[2] + lds_mse[3]));
        atomicAdd(&acc[1], (double)(lds_wcl[0] + lds_wcl[1] + lds_wcl[2] + lds_wcl[3]));
    }
}

__global__ void loss_finalize_kernel(const double* __restrict__ acc,
                                     float* __restrict__ out,
                                     double inv_count)
{
    if (threadIdx.x == 0 && blockIdx.x == 0) {
        out[0] = (float)(acc[0] * inv_count);
        out[1] = (float)(acc[1] * inv_count);
    }
}

extern "C" void kernel_launch(void* const* d_in, const int* in_sizes, int n_in,
                              void* d_out, int out_size, void* d_ws, size_t ws_size,
                              hipStream_t stream) {
    const float* input      = (const float*)d_in[0];
    const float* target     = (const float*)d_in[1];
    const float* weight     = (const float*)d_in[2];
    const float* sub_target = (const float*)d_in[3];
    const float* target_pre = (const float*)d_in[4];
    const float* sub_obrT   = (const float*)d_in[5];
    float* out = (float*)d_out;

    const int ND = in_sizes[0];      // N*D
    const int N  = in_sizes[2];      // weight length
    const int D  = ND / N;
    const int n4 = ND / 4;

    double* acc = (double*)d_ws;
    hipMemsetAsync(acc, 0, 2 * sizeof(double), stream);

    constexpr int NITER = 8;
    const int chunk = 256 * NITER;            // float4 per block
    if (D == 2048 && n4 % chunk == 0) {
        const int grid = n4 / chunk;          // 2048 for 8192x2048
        loss_pipe_kernel<NITER, 9><<<grid, 256, 0, stream>>>(
            (const float4*)input, (const float4*)target, weight,
            (const float4*)sub_target, (const float4*)target_pre,
            (const float4*)sub_obrT, acc, grid * 256);
    } else {
        int grid = (ND + 255) / 256;
        if (grid > 4096) grid = 4096;
        if (grid < 1) grid = 1;
        loss_reduce_generic<<<grid, 256, 0, stream>>>(
            input, target, weight, sub_target, target_pre, sub_obrT, acc, ND, D);
    }

    loss_finalize_kernel<<<1, 1, 0, stream>>>(acc, out, 1.0 / (double)ND);
}

// Round 4
// 61.861 us; speedup vs baseline: 3.5599x; 1.4071x over previous
//
#include <hip/hip_runtime.h>

#define EPS 1e-10f

// Stage 1: grid-stride fused dual-loss, static trip count.
// Requires n4 == gridDim.x * 256 * NITER (host guarantees).
// Each block writes one float2 partial {mse_sum, wcl_sum} to part[] --
// NO atomics (same-address f64 atomic bursts serialize across XCDs).
template<int NITER, int SHIFT>
__global__ __launch_bounds__(256) void loss_stage1_kernel(
    const float4* __restrict__ in4,
    const float4* __restrict__ tg4,
    const float*  __restrict__ weight,
    const float4* __restrict__ st4,
    const float4* __restrict__ tp4,
    const float4* __restrict__ so4,
    float2* __restrict__ part,
    int stride4)                    // gridDim.x * 256
{
    int i = blockIdx.x * 256 + threadIdx.x;

    float s_mse = 0.0f;
    float s_wcl = 0.0f;

#pragma unroll
    for (int k = 0; k < NITER; ++k, i += stride4) {
        float4 x  = in4[i];
        float4 t  = tg4[i];
        float4 st = st4[i];
        float4 tp = tp4[i];
        float4 so = so4[i];
        float  w  = weight[i >> SHIFT];

        const float w2 = w * w;
        float d0 = t.x - x.x, d1 = t.y - x.y;
        float d2 = t.z - x.z, d3 = t.w - x.w;
        s_mse += w2 * (d0 * d0);
        s_mse += w2 * (d1 * d1);
        s_mse += w2 * (d2 * d2);
        s_mse += w2 * (d3 * d3);

        float b0 = st.x * __logf(tp.x + EPS) + (1.0f - st.x) * __logf(1.0f - tp.x + EPS);
        float b1 = st.y * __logf(tp.y + EPS) + (1.0f - st.y) * __logf(1.0f - tp.y + EPS);
        float b2 = st.z * __logf(tp.z + EPS) + (1.0f - st.z) * __logf(1.0f - tp.z + EPS);
        float b3 = st.w * __logf(tp.w + EPS) + (1.0f - st.w) * __logf(1.0f - tp.w + EPS);
        s_wcl += fabsf(b0 * so.x);
        s_wcl += fabsf(b1 * so.y);
        s_wcl += fabsf(b2 * so.z);
        s_wcl += fabsf(b3 * so.w);
    }

    // wave (64-lane) shuffle reduction
    for (int off = 32; off > 0; off >>= 1) {
        s_mse += __shfl_down(s_mse, off, 64);
        s_wcl += __shfl_down(s_wcl, off, 64);
    }

    __shared__ float lds_mse[4];
    __shared__ float lds_wcl[4];
    int lane = threadIdx.x & 63;
    int wid  = threadIdx.x >> 6;
    if (lane == 0) {
        lds_mse[wid] = s_mse;
        lds_wcl[wid] = s_wcl;
    }
    __syncthreads();
    if (threadIdx.x == 0) {
        part[blockIdx.x] = make_float2(
            lds_mse[0] + lds_mse[1] + lds_mse[2] + lds_mse[3],
            lds_wcl[0] + lds_wcl[1] + lds_wcl[2] + lds_wcl[3]);
    }
}

// Stage 2: one block reduces nPart float2 partials, writes the 2 outputs.
__global__ __launch_bounds__(256) void loss_stage2_kernel(
    const float2* __restrict__ part,
    float* __restrict__ out,
    int nPart,
    float inv_count)
{
    float s_mse = 0.0f, s_wcl = 0.0f;
    for (int i = threadIdx.x; i < nPart; i += 256) {
        float2 p = part[i];
        s_mse += p.x;
        s_wcl += p.y;
    }
    for (int off = 32; off > 0; off >>= 1) {
        s_mse += __shfl_down(s_mse, off, 64);
        s_wcl += __shfl_down(s_wcl, off, 64);
    }
    __shared__ float lds_mse[4];
    __shared__ float lds_wcl[4];
    int lane = threadIdx.x & 63;
    int wid  = threadIdx.x >> 6;
    if (lane == 0) { lds_mse[wid] = s_mse; lds_wcl[wid] = s_wcl; }
    __syncthreads();
    if (threadIdx.x == 0) {
        out[0] = (lds_mse[0] + lds_mse[1] + lds_mse[2] + lds_mse[3]) * inv_count;
        out[1] = (lds_wcl[0] + lds_wcl[1] + lds_wcl[2] + lds_wcl[3]) * inv_count;
    }
}

// Generic fallback (arbitrary shapes): grid-stride, partials, then stage 2.
__global__ __launch_bounds__(256) void loss_generic_kernel(
    const float* __restrict__ input,
    const float* __restrict__ target,
    const float* __restrict__ weight,
    const float* __restrict__ sub_target,
    const float* __restrict__ target_pre,
    const float* __restrict__ sub_obrT,
    float2* __restrict__ part,
    int total, int D)
{
    float s_mse = 0.0f, s_wcl = 0.0f;
    int idx = blockIdx.x * blockDim.x + threadIdx.x;
    int stride = gridDim.x * blockDim.x;
    for (int i = idx; i < total; i += stride) {
        float w = weight[i / D];
        float d = target[i] - input[i];
        s_mse += w * w * d * d;
        float st = sub_target[i], tp = target_pre[i];
        float b = st * __logf(tp + EPS) + (1.0f - st) * __logf(1.0f - tp + EPS);
        s_wcl += fabsf(b * sub_obrT[i]);
    }
    for (int off = 32; off > 0; off >>= 1) {
        s_mse += __shfl_down(s_mse, off, 64);
        s_wcl += __shfl_down(s_wcl, off, 64);
    }
    __shared__ float lds_mse[4];
    __shared__ float lds_wcl[4];
    int lane = threadIdx.x & 63;
    int wid  = threadIdx.x >> 6;
    if (lane == 0) { lds_mse[wid] = s_mse; lds_wcl[wid] = s_wcl; }
    __syncthreads();
    if (threadIdx.x == 0) {
        part[blockIdx.x] = make_float2(
            lds_mse[0] + lds_mse[1] + lds_mse[2] + lds_mse[3],
            lds_wcl[0] + lds_wcl[1] + lds_wcl[2] + lds_wcl[3]);
    }
}

extern "C" void kernel_launch(void* const* d_in, const int* in_sizes, int n_in,
                              void* d_out, int out_size, void* d_ws, size_t ws_size,
                              hipStream_t stream) {
    const float* input      = (const float*)d_in[0];
    const float* target     = (const float*)d_in[1];
    const float* weight     = (const float*)d_in[2];
    const float* sub_target = (const float*)d_in[3];
    const float* target_pre = (const float*)d_in[4];
    const float* sub_obrT   = (const float*)d_in[5];
    float* out = (float*)d_out;

    const int ND = in_sizes[0];      // N*D
    const int N  = in_sizes[2];      // weight length
    const int D  = ND / N;
    const int n4 = ND / 4;

    float2* part = (float2*)d_ws;

    constexpr int NITER = 8;
    const int chunk = 256 * NITER;            // float4 per block
    if (D == 2048 && n4 % chunk == 0) {
        const int grid = n4 / chunk;          // 2048 for 8192x2048
        loss_stage1_kernel<NITER, 9><<<grid, 256, 0, stream>>>(
            (const float4*)input, (const float4*)target, weight,
            (const float4*)sub_target, (const float4*)target_pre,
            (const float4*)sub_obrT, part, grid * 256);
        loss_stage2_kernel<<<1, 256, 0, stream>>>(part, out, grid, 1.0f / (float)ND);
    } else {
        int grid = (ND + 255) / 256;
        if (grid > 2048) grid = 2048;
        if (grid < 1) grid = 1;
        loss_generic_kernel<<<grid, 256, 0, stream>>>(
            input, target, weight, sub_target, target_pre, sub_obrT, part, ND, D);
        loss_stage2_kernel<<<1, 256, 0, stream>>>(part, out, grid, 1.0f / (float)ND);
    }
}